// Round 5
// baseline (301.820 us; speedup 1.0000x reference)
//
#include <hip/hip_runtime.h>

typedef __attribute__((ext_vector_type(4))) float    float4v;
typedef __attribute__((ext_vector_type(8))) _Float16 half8v;
typedef __attribute__((ext_vector_type(4))) _Float16 half4v;

// Problem geometry (fixed by reference setup_inputs).
constexpr int B_ = 8;
constexpr int H_ = 480;
constexpr int W_ = 640;
constexpr int HW = H_ * W_;          // 307200
constexpr int N  = B_ * HW;          // 2457600 pixels
constexpr int WPP = 28;              // fp16 weights per pixel (27 + 1 pad -> 56 B)

// ---------------------------------------------------------------------------
// Weight precompute. 1 pixel/thread, all 3 dilation groups per thread.
// Weight layout: w[p][0..27] packed per pixel (56 B). Each wave's stores
// cover ONE dense 3.6 KB region (4 vector stores) -> single write stream.
// ---------------------------------------------------------------------------
__global__ __launch_bounds__(256) void wprep_kernel(
    const float* __restrict__ g1, const float* __restrict__ g2,
    const float* __restrict__ g3, const float* __restrict__ fuse,
    _Float16* __restrict__ w)
{
    const int p  = blockIdx.x * 256 + threadIdx.x;   // pixel id, < N
    const int b  = p / HW;
    const int hw = p - b * HW;

    _Float16 wl[WPP];
    wl[27] = (_Float16)0.f;

    const float* gs[3] = {g1, g2, g3};
#pragma unroll
    for (int d = 0; d < 3; ++d) {
        const float* gb = gs[d] + (size_t)b * 9 * HW + hw;
        float e[9];
        float m = -1e30f;
#pragma unroll
        for (int c = 0; c < 9; ++c) {
            e[c] = gb[(size_t)c * HW];
            m = fmaxf(m, e[c]);
        }
        float s = 0.f;
#pragma unroll
        for (int c = 0; c < 9; ++c) {
            e[c] = __expf(e[c] - m);
            s += e[c];
        }
        const float f = fuse[((size_t)b * 3 + d) * HW + hw] / s;
#pragma unroll
        for (int c = 0; c < 9; ++c)
            wl[d * 9 + c] = (_Float16)(e[c] * f);
    }

    _Float16* wp = w + (size_t)p * WPP;
    *(half8v*)(wp + 0)  = *(half8v*)(wl + 0);
    *(half8v*)(wp + 8)  = *(half8v*)(wl + 8);
    *(half8v*)(wp + 16) = *(half8v*)(wl + 16);
    *(half4v*)(wp + 24) = *(half4v*)(wl + 24);
}

// ---------------------------------------------------------------------------
// One propagation step. Weight reads: 4 vector loads per pixel (56 B packed).
// ---------------------------------------------------------------------------
__global__ __launch_bounds__(256) void prop_kernel(
    const float* __restrict__ xin, const _Float16* __restrict__ w,
    float* __restrict__ xout)
{
    const int j  = blockIdx.x * 64 + (threadIdx.x & 63);
    const int i  = blockIdx.y * 4  + (threadIdx.x >> 6);
    const int b  = blockIdx.z;
    const int hw = i * W_ + j;
    const int p  = b * HW + hw;

    const _Float16* wp = w + (size_t)p * WPP;
    const half8v w0 = *(const half8v*)(wp + 0);
    const half8v w1 = *(const half8v*)(wp + 8);
    const half8v w2 = *(const half8v*)(wp + 16);
    const half4v w3 = *(const half4v*)(wp + 24);

    _Float16 wl[27];
#pragma unroll
    for (int k = 0; k < 8; ++k) { wl[k] = w0[k]; wl[8 + k] = w1[k]; wl[16 + k] = w2[k]; }
#pragma unroll
    for (int k = 0; k < 3; ++k) wl[24 + k] = w3[k];

    const float* xb = xin + (size_t)b * HW;
    float acc = 0.f;
#pragma unroll
    for (int d = 1; d <= 3; ++d) {
#pragma unroll
        for (int ki = 0; ki < 3; ++ki) {
            const int ii = i + (ki - 1) * d;
            const bool vi = (unsigned)ii < (unsigned)H_;
#pragma unroll
            for (int kj = 0; kj < 3; ++kj) {
                const int jj = j + (kj - 1) * d;
                float xv = 0.f;
                if (vi && (unsigned)jj < (unsigned)W_)
                    xv = xb[ii * W_ + jj];
                acc = fmaf(xv, (float)wl[(d - 1) * 9 + ki * 3 + kj], acc);
            }
        }
    }
    xout[p] = acc;
}

// ---------------------------------------------------------------------------
extern "C" void kernel_launch(void* const* d_in, const int* in_sizes, int n_in,
                              void* d_out, int out_size, void* d_ws, size_t ws_size,
                              hipStream_t stream)
{
    const float* g1   = (const float*)d_in[0];
    const float* g2   = (const float*)d_in[1];
    const float* g3   = (const float*)d_in[2];
    const float* fuse = (const float*)d_in[3];
    const float* x    = (const float*)d_in[4];
    float* out = (float*)d_out;

    char* ws = (char*)d_ws;
    _Float16* w = (_Float16*)ws;                      // N*28*2 = 137.6 MB
    float* xa = (float*)(ws + (size_t)N * WPP * 2);   // ping
    float* xb = xa + N;                               // pong

    wprep_kernel<<<N / 256, 256, 0, stream>>>(g1, g2, g3, fuse, w);

    const dim3 pgrid(W_ / 64, H_ / 4, B_);
    const float* src = x;
    float* bufs[2] = {xa, xb};
    for (int t = 0; t < 8; ++t) {
        float* dst = (t == 7) ? out : bufs[t & 1];
        prop_kernel<<<pgrid, 256, 0, stream>>>(src, w, dst);
        src = dst;
    }
}

// Round 6
// 300.978 us; speedup vs baseline: 1.0028x; 1.0028x over previous
//
#include <hip/hip_runtime.h>
#include <stdint.h>

typedef __attribute__((ext_vector_type(4))) float    float4v;
typedef __attribute__((ext_vector_type(4))) _Float16 half4v;

// Problem geometry (fixed by reference setup_inputs).
constexpr int B_ = 8;
constexpr int H_ = 480;
constexpr int W_ = 640;
constexpr int HW = H_ * W_;          // 307200
constexpr int N  = B_ * HW;          // 2457600 pixels

constexpr int SEG = 1536;            // pixels per block segment (6 KB/plane)
constexpr int ROW = SEG + 4;         // LDS row pitch in floats (16B-aligned)

#define AS1 __attribute__((address_space(1)))
#define AS3 __attribute__((address_space(3)))

// ---------------------------------------------------------------------------
// Weight precompute, DMA-style. One (b,d) slice per blockIdx.y.
// Stage 9 guided planes into LDS: each wave streams ONE plane as consecutive
// 1 KB global_load_lds bursts (6 KB sequential run per stream) instead of the
// fine-grained interleave that has been stuck at ~2.4 TB/s.
// Then softmax+fuse from LDS, write planar fp16 w[27][N].
// ---------------------------------------------------------------------------
__global__ __launch_bounds__(384) void wprep_kernel(
    const float* __restrict__ g1, const float* __restrict__ g2,
    const float* __restrict__ g3, const float* __restrict__ fuse,
    _Float16* __restrict__ w)
{
    __shared__ float lds[9 * ROW];   // 9 * 1540 * 4 = 55.4 KB

    const int tid  = threadIdx.x;    // 0..383 (6 waves)
    const int wid  = tid >> 6;       // 0..5
    const int lane = tid & 63;
    const int z    = blockIdx.y;     // b*3 + d
    const int b    = z / 3;
    const int d    = z - 3 * b;
    const int seg0 = blockIdx.x * SEG;

    const float* gs3[3] = {g1, g2, g3};
    const float* gplane0 = gs3[d] + (size_t)b * 9 * HW + seg0;

    // --- staging: waves 0..5 -> planes 0..5, 6 bursts of 1 KB each ---
    {
        const float* src = gplane0 + (size_t)wid * HW;
        uint8_t* ldsrow = (uint8_t*)lds + (size_t)wid * (ROW * 4);
#pragma unroll
        for (int k = 0; k < 6; ++k) {
            __builtin_amdgcn_global_load_lds(
                (const AS1 uint32_t*)(src + k * 256 + lane * 4),
                (AS3 uint32_t*)(ldsrow + k * 1024),
                16, 0, 0);
        }
    }
    // --- planes 6..8: wave w covers plane 6+(w>>1), half (w&1) (3 KB) ---
    {
        const int pc   = 6 + (wid >> 1);
        const int half = wid & 1;
        const float* src = gplane0 + (size_t)pc * HW + half * (SEG / 2);
        uint8_t* ldsrow = (uint8_t*)lds + (size_t)pc * (ROW * 4) + half * (SEG * 2);
#pragma unroll
        for (int k = 0; k < 3; ++k) {
            __builtin_amdgcn_global_load_lds(
                (const AS1 uint32_t*)(src + k * 256 + lane * 4),
                (AS3 uint32_t*)(ldsrow + k * 1024),
                16, 0, 0);
        }
    }
    __syncthreads();   // drains vmcnt before any wave crosses

    // --- compute: each thread owns 4 consecutive pixels of the segment ---
    const int q0 = tid * 4;                       // 0..1532
    const size_t p = (size_t)b * HW + seg0 + q0;  // global pixel (aligned 4)

    float4v e[9];
    float4v m = {-1e30f, -1e30f, -1e30f, -1e30f};
#pragma unroll
    for (int c = 0; c < 9; ++c) {
        e[c] = *(const float4v*)&lds[c * ROW + q0];
#pragma unroll
        for (int k = 0; k < 4; ++k) m[k] = fmaxf(m[k], e[c][k]);
    }
    float4v s = {0.f, 0.f, 0.f, 0.f};
#pragma unroll
    for (int c = 0; c < 9; ++c)
#pragma unroll
        for (int k = 0; k < 4; ++k) { e[c][k] = __expf(e[c][k] - m[k]); s[k] += e[c][k]; }

    float4v f = *(const float4v*)(fuse + ((size_t)b * 3 + d) * HW + seg0 + q0);
#pragma unroll
    for (int k = 0; k < 4; ++k) f[k] /= s[k];

#pragma unroll
    for (int c = 0; c < 9; ++c) {
        half4v hv;
#pragma unroll
        for (int k = 0; k < 4; ++k) hv[k] = (_Float16)(e[c][k] * f[k]);
        *(half4v*)(w + (size_t)(d * 9 + c) * N + p) = hv;
    }
}

// ---------------------------------------------------------------------------
// One propagation step (round-3 proven kernel): out[p] = 27-tap x*w, fp16 w.
// 1 pixel/thread; wave covers 64 consecutive j -> all loads coalesced.
// ---------------------------------------------------------------------------
__global__ __launch_bounds__(256) void prop_kernel(
    const float* __restrict__ xin, const _Float16* __restrict__ w,
    float* __restrict__ xout)
{
    const int j  = blockIdx.x * 64 + (threadIdx.x & 63);
    const int i  = blockIdx.y * 4  + (threadIdx.x >> 6);
    const int b  = blockIdx.z;
    const int hw = i * W_ + j;
    const int p  = b * HW + hw;

    const float* xb = xin + (size_t)b * HW;
    float acc = 0.f;
#pragma unroll
    for (int d = 1; d <= 3; ++d) {
#pragma unroll
        for (int ki = 0; ki < 3; ++ki) {
            const int ii = i + (ki - 1) * d;
            const bool vi = (unsigned)ii < (unsigned)H_;
#pragma unroll
            for (int kj = 0; kj < 3; ++kj) {
                const int jj = j + (kj - 1) * d;
                float xv = 0.f;
                if (vi && (unsigned)jj < (unsigned)W_)
                    xv = xb[ii * W_ + jj];
                const int plane = (d - 1) * 9 + ki * 3 + kj;
                acc = fmaf(xv, (float)w[(size_t)plane * N + p], acc);
            }
        }
    }
    xout[p] = acc;
}

// ---------------------------------------------------------------------------
extern "C" void kernel_launch(void* const* d_in, const int* in_sizes, int n_in,
                              void* d_out, int out_size, void* d_ws, size_t ws_size,
                              hipStream_t stream)
{
    const float* g1   = (const float*)d_in[0];
    const float* g2   = (const float*)d_in[1];
    const float* g3   = (const float*)d_in[2];
    const float* fuse = (const float*)d_in[3];
    const float* x    = (const float*)d_in[4];
    float* out = (float*)d_out;

    char* ws = (char*)d_ws;
    _Float16* w = (_Float16*)ws;                    // 27*N*2 = 132.7 MB
    float* xa = (float*)(ws + (size_t)27 * N * 2);  // ping
    float* xb = xa + N;                             // pong

    // wprep: HW/SEG = 200 segments per slice, 24 slices.
    wprep_kernel<<<dim3(HW / SEG, B_ * 3), 384, 0, stream>>>(g1, g2, g3, fuse, w);

    const dim3 pgrid(W_ / 64, H_ / 4, B_);
    const float* src = x;
    float* bufs[2] = {xa, xb};
    for (int t = 0; t < 8; ++t) {
        float* dst = (t == 7) ? out : bufs[t & 1];
        prop_kernel<<<pgrid, 256, 0, stream>>>(src, w, dst);
        src = dst;
    }
}